// Round 2
// baseline (1243.655 us; speedup 1.0000x reference)
//
#include <hip/hip_runtime.h>

typedef short s16x8 __attribute__((ext_vector_type(8)));
typedef float f32x4 __attribute__((ext_vector_type(4)));

#define NB    128
#define NTOK  996
#define NPAD  1024
#define NGRP  4
#define GSZ   256
#define NLAY  8

__device__ __forceinline__ float bf2f(unsigned short u){
    unsigned int v = ((unsigned int)u) << 16;
    return __uint_as_float(v);
}
__device__ __forceinline__ unsigned short f2bf(float f){
    unsigned int x = __float_as_uint(f);
    unsigned int r = (x + 0x7fffu + ((x >> 16) & 1u)) >> 16;
    return (unsigned short)r;
}
__device__ __forceinline__ unsigned int packbf(float a, float b){
    return (unsigned int)f2bf(a) | ((unsigned int)f2bf(b) << 16);
}
__device__ __forceinline__ float silu(float v){
    return v / (1.0f + __expf(-v));
}

// derive one MFMA A/B fragment (8 dims at d0) of gamma*qk+beta with rotary
__device__ __forceinline__ s16x8 derive_core(const unsigned short* __restrict__ qrow, int d0,
        float4 g0, float4 g1, float4 b0, float4 b1,
        const float* __restrict__ rp, bool rot){
    uint4 u = *(const uint4*)(qrow + d0);
    float y0 = bf2f((unsigned short)(u.x & 0xffffu))*g0.x + b0.x;
    float y1 = bf2f((unsigned short)(u.x >> 16))    *g0.y + b0.y;
    float y2 = bf2f((unsigned short)(u.y & 0xffffu))*g0.z + b0.z;
    float y3 = bf2f((unsigned short)(u.y >> 16))    *g0.w + b0.w;
    float y4 = bf2f((unsigned short)(u.z & 0xffffu))*g1.x + b1.x;
    float y5 = bf2f((unsigned short)(u.z >> 16))    *g1.y + b1.y;
    float y6 = bf2f((unsigned short)(u.w & 0xffffu))*g1.z + b1.z;
    float y7 = bf2f((unsigned short)(u.w >> 16))    *g1.w + b1.w;
    if (rot){
        float4 c4 = *(const float4*)(rp);
        float4 s4 = *(const float4*)(rp + 16);
        float a;
        a = y0; y0 = a*c4.x - y1*s4.x; y1 = y1*c4.x + a*s4.x;
        a = y2; y2 = a*c4.y - y3*s4.y; y3 = y3*c4.y + a*s4.y;
        a = y4; y4 = a*c4.z - y5*s4.z; y5 = y5*c4.z + a*s4.z;
        a = y6; y6 = a*c4.w - y7*s4.w; y7 = y7*c4.w + a*s4.w;
    }
    union { unsigned int uu[4]; s16x8 s; } r;
    r.uu[0] = packbf(y0, y1);
    r.uu[1] = packbf(y2, y3);
    r.uu[2] = packbf(y4, y5);
    r.uu[3] = packbf(y6, y7);
    return r.s;
}

// ---------------- embed + positional (+ rope table) ----------------
__global__ __launch_bounds__(256) void k_embed(const int* __restrict__ kmer,
                                               const float* __restrict__ emb,
                                               const float* __restrict__ ps,
                                               float* __restrict__ x,
                                               float* __restrict__ rope){
    int gid = blockIdx.x * 256 + threadIdx.x;
    if (gid < NPAD){
        float tf2 = (float)gid;
        #pragma unroll
        for (int i = 0; i < 16; i++){
            float inv = expf(((float)(2*i) / 32.0f) * -9.210340371976184f);
            float ang = tf2 * inv;
            rope[gid*32 + i]      = cosf(ang);
            rope[gid*32 + 16 + i] = sinf(ang);
        }
    }
    if (gid >= NB * NTOK) return;
    int b = gid / NTOK;
    int tt = gid - b * NTOK;
    int idx = kmer[gid];
    const float* er = emb + (size_t)idx * 16;
    float pscale = ps[0];
    float tf = (float)tt;
    float* xr = x + (size_t)gid * 16;
    #pragma unroll
    for (int i = 0; i < 8; i++){
        float inv = expf(((float)(2*i) / 16.0f) * -9.210340371976184f);
        float ang = tf * inv;
        xr[i]     = er[i]     + sinf(ang) * pscale;
        xr[8 + i] = er[8 + i] + cosf(ang) * pscale;
    }
}

// ---------------- per-layer tokenwise + fused lin_kv partial ----------------
// R2: 512 threads, all global stores deferred to after the last barrier
// (in-loop __syncthreads emits vmcnt(0) and drained scattered stores before);
// vT/linkvp stores via wave-local LDS transpose -> coalesced 16B stores.
// MFMA K=32 fragments REQUIRE 32-short rows: stride 40 restored (R1 bug:
// stride 24 made quad==3 read the next row -> NaN). LDS phase-aliased:
// WcT resident [0,15360); As [15360,35840) dead after bfr preload, overlaid
// by LkT [15360,50176); Vt [50176,58880). wf re-read from LDS per round
// (saves 48 VGPRs; keeps us under the 128-VGPR 2-block/CU cap).
__global__ __launch_bounds__(512, 4) void k_pre(const float* __restrict__ x,
                                             const float* __restrict__ Wh, const float* __restrict__ bh,
                                             const float* __restrict__ Wqk, const float* __restrict__ bqk,
                                             const float* __restrict__ norm_g,
                                             const float* __restrict__ gamma, const float* __restrict__ beta,
                                             const float* __restrict__ rope, int layer,
                                             unsigned short* __restrict__ qk,
                                             unsigned short* __restrict__ vT,
                                             unsigned short* __restrict__ gateb,
                                             float* __restrict__ linkvp){
    __shared__ __align__(16) unsigned char sm[58880];
    unsigned short* WcT = (unsigned short*)sm;             // [192][40] dims0..15,16=bias,17..31=0
    unsigned short* As  = (unsigned short*)(sm + 15360);   // [256][40] token fragments (phase 1)
    unsigned short* LkT = (unsigned short*)(sm + 15360);   // [128][136] lin_k chunk (phase 2, aliases As)
    unsigned short* Vt  = (unsigned short*)(sm + 50176);   // [32][136]  v chunk
    int tid = threadIdx.x;
    int qt = blockIdx.x & 3, b = blockIdx.x >> 2;
    const float* Whl = Wh  + (size_t)layer * 1024;
    const float* Wql = Wqk + (size_t)layer * 2048;
    const float* gLin = gamma + (size_t)layer * 512 + 384;
    const float* bLin = beta  + (size_t)layer * 512 + 384;
    for (int i = tid; i < 1024; i += 512){ int d = i >> 6, c2 = i & 63;  WcT[c2*40 + d] = f2bf(Whl[i]); }
    for (int i = tid; i < 2048; i += 512){ int d = i >> 7, c2 = i & 127; WcT[(64 + c2)*40 + d] = f2bf(Wql[i]); }
    if (tid < 192){
        int i = tid;
        float bv = (i < 64) ? bh[layer*64 + i] : bqk[layer*128 + (i - 64)];
        WcT[i*40 + 16] = f2bf(bv);
        WcT[i*40 + 17] = 0;
        unsigned int* zz = (unsigned int*)(WcT + i*40 + 18);
        #pragma unroll
        for (int k = 0; k < 7; k++) zz[k] = 0u;
    }
    float g = norm_g[layer];
    if (tid < 256){
        int tt = qt*256 + tid;
        int tsafe = tt < NTOK ? tt : (NTOK - 1);
        unsigned int* dd = (unsigned int*)(As + tid * 40);
        const float4* xr4 = (const float4*)(x + ((size_t)b*NTOK + tsafe) * 16);
        float cur[16];
        float s2 = 0.f;
        #pragma unroll
        for (int c2 = 0; c2 < 4; c2++){
            float4 v4 = xr4[c2];
            cur[4*c2] = v4.x; cur[4*c2+1] = v4.y; cur[4*c2+2] = v4.z; cur[4*c2+3] = v4.w;
        }
        #pragma unroll
        for (int d = 0; d < 16; d++) s2 += cur[d]*cur[d];
        float sc = g / fmaxf(sqrtf(s2) * 0.25f, 1e-5f);
        #pragma unroll
        for (int i = 0; i < 4; i++) dd[4 + i] = packbf(cur[8 + 2*i]*sc, cur[9 + 2*i]*sc);
        dd[8] = 0x00003f80u; // dim16 = 1.0 (bias lane)
        #pragma unroll
        for (int i = 9; i < 16; i++) dd[i] = 0u;
        if (tid < 255){      // write NEXT token's shifted half (structural shift)
            unsigned int* ddn = (unsigned int*)(As + (tid+1) * 40);
            #pragma unroll
            for (int i = 0; i < 4; i++) ddn[i] = packbf(cur[2*i]*sc, cur[2*i+1]*sc);
        }
        if (tid == 0){
            if (tt == 0){
                dd[0] = 0u; dd[1] = 0u; dd[2] = 0u; dd[3] = 0u;
            } else {
                const float4* xp4 = (const float4*)(x + ((size_t)b*NTOK + tt - 1) * 16);
                float prv[16]; float p2 = 0.f;
                #pragma unroll
                for (int c2 = 0; c2 < 4; c2++){
                    float4 v4 = xp4[c2];
                    prv[4*c2] = v4.x; prv[4*c2+1] = v4.y; prv[4*c2+2] = v4.z; prv[4*c2+3] = v4.w;
                }
                #pragma unroll
                for (int d = 0; d < 16; d++) p2 += prv[d]*prv[d];
                float sp = g / fmaxf(sqrtf(p2) * 0.25f, 1e-5f);
                #pragma unroll
                for (int i = 0; i < 4; i++) dd[i] = packbf(prv[2*i]*sp, prv[2*i+1]*sp);
            }
        }
    }
    __syncthreads();   // WcT + As ready
    int w = tid >> 6, lane = tid & 63, m16 = lane & 15, quad = lane >> 4;
    s16x8 bfr[2];
    #pragma unroll
    for (int nt = 0; nt < 2; nt++)
        bfr[nt] = *(const s16x8*)(As + (w*32 + nt*16 + m16)*40 + quad*8);
    __syncthreads();   // As dead; LkT/Vt region reusable
    f32x4 zacc = {0.f,0.f,0.f,0.f};
    f32x4 lacc[2] = {{0,0,0,0},{0,0,0,0}};
    unsigned int qku[2][8][2];   // deferred qk (bf16x2 packed)
    unsigned int gu_[2][2][2];   // deferred gate
    unsigned int vpk[2][2][2];   // deferred v (masked)
    int c = w*16 + m16;          // column in 128-token chunk staging
    #pragma unroll
    for (int nt = 0; nt < 2; nt++){
        int ttk = qt*256 + w*32 + nt*16 + m16;
        bool tv = ttk < NTOK;
        #pragma unroll
        for (int mi = 0; mi < 12; mi++){
            s16x8 wfm = *(const s16x8*)(WcT + (mi*16 + m16)*40 + quad*8);
            f32x4 r = __builtin_amdgcn_mfma_f32_16x16x32_bf16(wfm, bfr[nt], zacc, 0, 0, 0);
            float sv[4];
            #pragma unroll
            for (int reg = 0; reg < 4; reg++) sv[reg] = silu(r[reg]);
            int wc0 = mi*16 + quad*4;
            if (mi < 2){
                unsigned short p0 = tv ? f2bf(sv[0]) : (unsigned short)0;
                unsigned short p1 = tv ? f2bf(sv[1]) : (unsigned short)0;
                unsigned short p2 = tv ? f2bf(sv[2]) : (unsigned short)0;
                unsigned short p3 = tv ? f2bf(sv[3]) : (unsigned short)0;
                Vt[(wc0+0)*136 + c] = p0;
                Vt[(wc0+1)*136 + c] = p1;
                Vt[(wc0+2)*136 + c] = p2;
                Vt[(wc0+3)*136 + c] = p3;
                vpk[nt][mi][0] = (unsigned int)p0 | ((unsigned int)p1 << 16);
                vpk[nt][mi][1] = (unsigned int)p2 | ((unsigned int)p3 << 16);
            } else if (mi < 4){
                gu_[nt][mi-2][0] = packbf(sv[0], sv[1]);
                gu_[nt][mi-2][1] = packbf(sv[2], sv[3]);
            } else {
                int qd = wc0 - 64;
                qku[nt][mi-4][0] = packbf(sv[0], sv[1]);
                qku[nt][mi-4][1] = packbf(sv[2], sv[3]);
                float y0 = sv[0]*gLin[qd]   + bLin[qd];
                float y1 = sv[1]*gLin[qd+1] + bLin[qd+1];
                float y2 = sv[2]*gLin[qd+2] + bLin[qd+2];
                float y3 = sv[3]*gLin[qd+3] + bLin[qd+3];
                if (qd < 32){
                    const float* rp = rope + ttk*32 + (qd >> 1);
                    float c0 = rp[0], s0 = rp[16], c1 = rp[1], s1 = rp[17];
                    float a;
                    a = y0; y0 = a*c0 - y1*s0; y1 = y1*c0 + a*s0;
                    a = y2; y2 = a*c1 - y3*s1; y3 = y3*c1 + a*s1;
                }
                LkT[(qd+0)*136 + c] = f2bf(y0);
                LkT[(qd+1)*136 + c] = f2bf(y1);
                LkT[(qd+2)*136 + c] = f2bf(y2);
                LkT[(qd+3)*136 + c] = f2bf(y3);
            }
        }
        __syncthreads();   // LkT/Vt 128-token chunk ready (no global stores to drain)
        #pragma unroll
        for (int ks2 = 0; ks2 < 4; ks2++){
            s16x8 a  = *(const s16x8*)(LkT + (w*16 + m16)*136 + ks2*32 + quad*8);
            s16x8 b0 = *(const s16x8*)(Vt + (m16)*136 + ks2*32 + quad*8);
            s16x8 b1 = *(const s16x8*)(Vt + (16 + m16)*136 + ks2*32 + quad*8);
            lacc[0] = __builtin_amdgcn_mfma_f32_16x16x32_bf16(a, b0, lacc[0], 0,0,0);
            lacc[1] = __builtin_amdgcn_mfma_f32_16x16x32_bf16(a, b1, lacc[1], 0,0,0);
        }
        __syncthreads();   // chunk reads done (also frees whole LDS for epilogue)
    }
    // ---- epilogue: all global stores issued here, drained once at kernel end ----
    #pragma unroll
    for (int nt = 0; nt < 2; nt++){
        size_t rowq = (size_t)b*NPAD + qt*256 + w*32 + nt*16 + m16;
        #pragma unroll
        for (int mi8 = 0; mi8 < 8; mi8++)
            *(uint2*)(qk + rowq*128 + mi8*16 + quad*4) = make_uint2(qku[nt][mi8][0], qku[nt][mi8][1]);
        *(uint2*)(gateb + rowq*32 + quad*4)      = make_uint2(gu_[nt][0][0], gu_[nt][0][1]);
        *(uint2*)(gateb + rowq*32 + 16 + quad*4) = make_uint2(gu_[nt][1][0], gu_[nt][1][1]);
    }
    // vT: wave-local LDS transpose -> coalesced 16B stores (aliases dead WcT/As)
    {
        unsigned short* mv = (unsigned short*)sm + w*1280;   // [32 e][40 tok-pad]
        #pragma unroll
        for (int nt = 0; nt < 2; nt++){
            #pragma unroll
            for (int mi = 0; mi < 2; mi++){
                int e0 = mi*16 + quad*4;
                mv[(e0+0)*40 + nt*16 + m16] = (unsigned short)(vpk[nt][mi][0] & 0xffffu);
                mv[(e0+1)*40 + nt*16 + m16] = (unsigned short)(vpk[nt][mi][0] >> 16);
                mv[(e0+2)*40 + nt*16 + m16] = (unsigned short)(vpk[nt][mi][1] & 0xffffu);
                mv[(e0+3)*40 + nt*16 + m16] = (unsigned short)(vpk[nt][mi][1] >> 16);
            }
        }
        #pragma unroll
        for (int r2 = 0; r2 < 2; r2++){
            int e = r2*16 + (lane >> 2);
            int cc = (lane & 3) * 8;
            s16x8 vv = *(const s16x8*)(mv + e*40 + cc);
            *(s16x8*)(vT + ((size_t)b*32 + e)*NPAD + qt*256 + w*32 + cc) = vv;
        }
    }
    // linkv partial: wave-local LDS transpose -> coalesced float4 stores
    {
        float* ml = (float*)(sm + 20480) + w*512;   // [32 e][16 d]
        const float invn = 1.0f / 996.0f;
        #pragma unroll
        for (int j = 0; j < 2; j++)
            #pragma unroll
            for (int reg = 0; reg < 4; reg++)
                ml[(j*16 + m16)*16 + quad*4 + reg] = lacc[j][reg] * invn;
        #pragma unroll
        for (int r2 = 0; r2 < 2; r2++){
            int e = r2*16 + (lane >> 2);
            int dc = (lane & 3) * 4;
            float4 vv = *(const float4*)(ml + e*16 + dc);
            *(float4*)(linkvp + (((size_t)qt*NB + b)*32 + e)*128 + w*16 + dc) = vv;
        }
    }
}

// ---------------- quad attention + lin_out + gate + Wo + residual ----------------
// R15 structure + R2 software pipeline: K chunk's qk+rope prefetched to
// REGISTERS one chunk ahead (register loads survive barriers; only the use
// waits), V fragments hoisted to chunk top (latency hidden under derive+S),
// epilogue x/gate prefetched under the lin path. lkv register prefetch
// dropped (32 VGPRs live across the loop would break the 128-VGPR cap).
// LDS row strides stay multiples of 8 shorts (R17 lesson).
#define KD_BYTES (64*136*2)
#define PW_BYTES (8*32*72*2)
__global__ __launch_bounds__(512, 4) void k_quad(const unsigned short* __restrict__ qk,
                                              const unsigned short* __restrict__ vT,
                                              const unsigned short* __restrict__ gateb,
                                              const float* __restrict__ linkvp,
                                              const float* __restrict__ rope,
                                              const float* __restrict__ gamma, const float* __restrict__ beta,
                                              int layer,
                                              const float* __restrict__ Wo, const float* __restrict__ bo,
                                              float* __restrict__ x){
    __shared__ __align__(16) unsigned char smem[KD_BYTES + PW_BYTES];
    __shared__ __align__(16) unsigned short LkBs[32 * 136]; // lin_kv B-fragments [e][d]
    __shared__ float sWo[512];
    __shared__ float sbo[16];
    unsigned short* Kd = (unsigned short*)smem;
    unsigned short* Pw = (unsigned short*)(smem + KD_BYTES);
    int tid = threadIdx.x;
    int blk = blockIdx.x;
    int g = blk & 3, b = blk >> 2;
    int tg0 = g * GSZ;
    const float* gamL = gamma + (size_t)layer * 512;
    const float* betL = beta  + (size_t)layer * 512;
    sWo[tid] = Wo[layer*512 + tid];
    if (tid < 16) sbo[tid] = bo[layer*16 + tid];

    int w = tid >> 6, lane = tid & 63, m16 = lane & 15, quad = lane >> 4;

    // ---- derive quad_q fragments into registers (wave w owns q rows [w*32, w*32+32)) ----
    int tqA = tg0 + w*32 + m16;
    int tqB = tqA + 16;
    const unsigned short* qrowA = qk + ((size_t)b*NPAD + tqA)*128;
    const unsigned short* qrowB = qk + ((size_t)b*NPAD + tqB)*128;
    const float* rpA = rope + tqA*32 + quad*4;
    const float* rpB = rope + tqB*32 + quad*4;
    s16x8 qf[2][4];
    #pragma unroll
    for (int ks = 0; ks < 4; ks++){
        int d0 = ks*32 + quad*8;
        float4 g0 = *(const float4*)(gamL + d0), g1 = *(const float4*)(gamL + d0 + 4);
        float4 b0 = *(const float4*)(betL + d0), b1 = *(const float4*)(betL + d0 + 4);
        bool rot = (ks == 0) && (quad < 4);
        qf[0][ks] = derive_core(qrowA, d0, g0,g1,b0,b1, rpA, rot);
        qf[1][ks] = derive_core(qrowB, d0, g0,g1,b0,b1, rpB, rot);
    }

    const float* gK = gamL + 256;
    const float* bK = betL + 256;
    f32x4 oacc[2][2] = {{{0,0,0,0},{0,0,0,0}},{{0,0,0,0},{0,0,0,0}}};
    unsigned short* myP = Pw + w*32*72;   // 32 rows per wave (both sub-tiles)

    // ---- K-staging geometry + one-chunk-ahead register prefetch ----
    int kr = tid >> 3, seg = (tid & 7) * 16;
    uint4 pku0, pku1;
    float4 prc0, prc1, prs0, prs1;
    auto LOADK = [&](int ch){
        int tk = tg0 + ch*64 + kr;
        const unsigned short* krow = qk + ((size_t)b*NPAD + tk)*128 + seg;
        pku0 = ((const uint4*)krow)[0];
        pku1 = ((const uint4*)krow)[1];
        const float* rpk = rope + (seg < 32 ? (tk*32 + (seg >> 1)) : 0);
        prc0 = *(const float4*)(rpk);
        prs0 = *(const float4*)(rpk + 16);
        prc1 = *(const float4*)(rpk + 4);
        prs1 = *(const float4*)(rpk + 20);
    };
    LOADK(0);

    for (int ch = 0; ch < 4; ch++){
        // V-fragment prefetch: consumed by PV at chunk end; latency hidden
        s16x8 vf[2][2];
        #pragma unroll
        for (int ks2 = 0; ks2 < 2; ks2++){
            vf[ks2][0] = *(const s16x8*)(vT + ((size_t)b*32 + m16)*NPAD + tg0 + ch*64 + ks2*32 + quad*8);
            vf[ks2][1] = *(const s16x8*)(vT + ((size_t)b*32 + 16 + m16)*NPAD + tg0 + ch*64 + ks2*32 + quad*8);
        }
        // derive this chunk's K from prefetched regs (no LDS/global dependency)
        uint4 kd0, kd1;
        {
            #pragma unroll
            for (int h = 0; h < 2; h++){
                uint4 u = h ? pku1 : pku0;
                unsigned int uu[4] = {u.x, u.y, u.z, u.w};
                float y[8];
                #pragma unroll
                for (int k = 0; k < 4; k++){
                    int d = h*8 + 2*k;
                    y[2*k]   = bf2f((unsigned short)(uu[k] & 0xffffu)) * gK[seg + d]     + bK[seg + d];
                    y[2*k+1] = bf2f((unsigned short)(uu[k] >> 16))     * gK[seg + d + 1] + bK[seg + d + 1];
                }
                if (seg < 32){
                    float cc[4], ss[4];
                    if (h){ cc[0]=prc1.x; cc[1]=prc1.y; cc[2]=prc1.z; cc[3]=prc1.w;
                            ss[0]=prs1.x; ss[1]=prs1.y; ss[2]=prs1.z; ss[3]=prs1.w; }
                    else  { cc[0]=prc0.x; cc[1]=prc0.y; cc[2]=prc0.z; cc[3]=prc0.w;
                            ss[0]=prs0.x; ss[1]=prs0.y; ss[2]=prs0.z; ss[3]=prs0.w; }
                    #pragma unroll
                    for (int p2 = 0; p2 < 4; p2++){
                        float a = y[2*p2], d2 = y[2*p2+1];
                        y[2*p2]   = a*cc[p2] - d2*ss[p2];
                        y[2*p2+1] = d2*cc[p2] + a*ss[p2];
                    }
                }
                uint4 kk = make_uint4(packbf(y[0],y[1]), packbf(y[2],y[3]),
                                      packbf(y[4],y[5]), packbf(y[6],y[7]));
                if (h) kd1 = kk; else kd0 = kk;
            }
        }
        __syncthreads();   // all waves done reading prev Kd; covers sWo on ch==0
        *(uint4*)(Kd + kr*136 + seg)     = kd0;
        *(uint4*)(Kd + kr*136 + seg + 8) = kd1;
        if (ch < 3) LOADK(ch + 1);   // next chunk's qk/rope loads stay in flight across barrier
        __syncthreads();   // Kd ready
        // ---- S for BOTH q sub-tiles per np (kf read once, feeds 4 MFMAs) ----
        #pragma unroll
        for (int np = 0; np < 2; np++){
            f32x4 s00 = {0,0,0,0}, s01 = {0,0,0,0}, s10 = {0,0,0,0}, s11 = {0,0,0,0};
            #pragma unroll
            for (int ks = 0; ks < 4; ks++){
                s16x8 kf0 = *(const s16x8*)(Kd + ((np*2  )*16 + m16)*136 + ks*32 + quad*8);
                s16x8 kf1 = *(const s16x8*)(Kd + ((np*2+1)*16 + m16)*136 + ks*32 + quad*8);
                s00 = __builtin_amdgcn_mfma_f32_16x16x32_bf16(qf[0][ks], kf0, s00, 0,0,0);
                s01 = __builtin_amdgcn_mfma_f32_16x16x32_bf16(qf[0][ks], kf1, s01, 0,0,0);
                s10 = __builtin_amdgcn_mfma_f32_16x16x32_bf16(qf[1][ks], kf0, s10, 0,0,0);
                s11 = __builtin_amdgcn_mfma_f32_16x16x32_bf16(qf[1][ks], kf1, s11, 0,0,0);
            }
            #pragma unroll
            for (int j = 0; j < 2; j++){
                int kl = (np*2 + j)*16 + m16;
                bool kv = (tg0 + ch*64 + kl) < NTOK;
                #pragma unroll
                for (int reg = 0; reg < 4; reg++){
                    float a0 = fmaxf(j ? s01[reg] : s00[reg], 0.0f);
                    float a1 = fmaxf(j ? s11[reg] : s10[reg], 0.0f);
                    a0 = a0 * a0;
                    a1 = a1 * a1;
                    myP[(quad*4 + reg)*72 + kl]      = kv ? f2bf(a0) : (unsigned short)0;
                    myP[(16 + quad*4 + reg)*72 + kl] = kv ? f2bf(a1) : (unsigned short)0;
                }
            }
        }
        // ---- PV: both sub-tiles, V fragments from registers ----
        #pragma unroll
        for (int i = 0; i < 2; i++){
            #pragma unroll
            for (int ks2 = 0; ks2 < 2; ks2++){
                s16x8 pa = *(const s16x8*)(myP + (i*16 + m16)*72 + ks2*32 + quad*8);
                oacc[i][0] = __builtin_amdgcn_mfma_f32_16x16x32_bf16(pa, vf[ks2][0], oacc[i][0], 0,0,0);
                oacc[i][1] = __builtin_amdgcn_mfma_f32_16x16x32_bf16(pa, vf[ks2][1], oacc[i][1], 0,0,0);
            }
        }
    }
    // fold the (1/256)^2 quad scale
    const float qsc = 1.0f / 65536.0f;
    #pragma unroll
    for (int i = 0; i < 2; i++)
        #pragma unroll
        for (int j = 0; j < 2; j++)
            oacc[i][j] = oacc[i][j] * qsc;
    // ---- stage lin_kv B-fragments: sum 4 fp32 partials -> bf16 LDS ----
    {
        int e = tid >> 4, dbase = (tid & 15) * 8;
        float s[8];
        #pragma unroll
        for (int k = 0; k < 8; k++) s[k] = 0.f;
        #pragma unroll
        for (int part = 0; part < 4; part++){
            const float* src = linkvp + (((size_t)part*NB + b)*32 + e)*128 + dbase;
            float4 u0 = *(const float4*)src;
            float4 u1 = *(const float4*)(src + 4);
            s[0]+=u0.x; s[1]+=u0.y; s[2]+=u0.z; s[3]+=u0.w;
            s[4]+=u1.x; s[5]+=u1.y; s[6]+=u1.z; s[7]+=u1.w;
        }
        unsigned int* dst = (unsigned int*)(LkBs + e*136 + dbase);
        #pragma unroll
        for (int k = 0; k < 4; k++) dst[k] = packbf(s[2*k], s[2*k+1]);
    }
    __syncthreads();   // LkBs ready; all waves done with Kd/Pw (safe for O-stage reuse)
    // ---- epilogue operand prefetch (hidden under lin path) ----
    int pr = lane >> 1, dp2 = (lane & 1) * 8;
    int p = tg0 + w*32 + pr;
    bool pvld = p < NTOK;
    int psafe = pvld ? p : (NTOK - 1);
    const unsigned short* gr = gateb + ((size_t)b*NPAD + psafe)*32;
    uint4 egu[4];
    #pragma unroll
    for (int eh = 0; eh < 4; eh++) egu[eh] = *(const uint4*)(gr + eh*8);
    float* xr = x + ((size_t)b*NTOK + psafe)*16 + dp2;
    float4 ex0 = *(const float4*)xr;
    float4 ex1 = *(const float4*)(xr + 4);
    // ---- lin path: lin_q (in-register derive) @ LkBs ----
    {
        const float* gamQ = gamL + 128;
        const float* betQ = betL + 128;
        #pragma unroll
        for (int ks = 0; ks < 4; ks++){
            int d0 = ks*32 + quad*8;
            float4 g0 = *(const float4*)(gamQ + d0), g1 = *(const float4*)(gamQ + d0 + 4);
            float4 b0 = *(const float4*)(betQ + d0), b1 = *(const float4*)(betQ + d0 + 4);
            bool rot = (ks == 0) && (quad < 4);
            s16x8 lf0 = derive_core(qrowA, d0, g0,g1,b0,b1, rpA, rot);
            s16x8 lf1 = derive_core(qrowB, d0, g0,g1,b0,b1, rpB, rot);
            #pragma unroll
            for (int j = 0; j < 2; j++){
                s16x8 lb = *(const s16x8*)(LkBs + (j*16 + m16)*136 + ks*32 + quad*8);
                oacc[0][j] = __builtin_amdgcn_mfma_f32_16x16x32_bf16(lf0, lb, oacc[0][j], 0,0,0);
                oacc[1][j] = __builtin_amdgcn_mfma_f32_16x16x32_bf16(lf1, lb, oacc[1][j], 0,0,0);
            }
        }
    }
    // ---- stage O (per-wave slice of the smem arena, as floats; within-wave only) ----
    float* Obw = (float*)smem + w*1056;  // 32 rows x stride 33 = 4224 B/wave
    #pragma unroll
    for (int i = 0; i < 2; i++)
        #pragma unroll
        for (int j = 0; j < 2; j++)
            #pragma unroll
            for (int reg = 0; reg < 4; reg++)
                Obw[(i*16 + quad*4 + reg)*33 + j*16 + m16] = oacc[i][j][reg];
    // ---- epilogue: x += (gate .* O) @ Wo + bo (per-wave rows, operands preloaded) ----
    if (pvld){
        float a[8] = { sbo[dp2]+ex0.x, sbo[dp2+1]+ex0.y, sbo[dp2+2]+ex0.z, sbo[dp2+3]+ex0.w,
                       sbo[dp2+4]+ex1.x, sbo[dp2+5]+ex1.y, sbo[dp2+6]+ex1.z, sbo[dp2+7]+ex1.w };
        #pragma unroll
        for (int eh = 0; eh < 4; eh++){
            unsigned int gg[4] = {egu[eh].x, egu[eh].y, egu[eh].z, egu[eh].w};
            #pragma unroll
            for (int k = 0; k < 4; k++){
                float gv0 = bf2f((unsigned short)(gg[k] & 0xffffu));
                float gv1 = bf2f((unsigned short)(gg[k] >> 16));
                int e = eh*8 + 2*k;
                float ov0 = Obw[pr*33 + e] * gv0;
                float ov1 = Obw[pr*33 + e + 1] * gv1;
                const float* wr0 = &sWo[e*16 + dp2];
                const float* wr1 = &sWo[(e+1)*16 + dp2];
                #pragma unroll
                for (int kk = 0; kk < 8; kk++) a[kk] += ov0 * wr0[kk] + ov1 * wr1[kk];
            }
        }
        *(float4*)xr = make_float4(a[0],a[1],a[2],a[3]);
        *(float4*)(xr+4) = make_float4(a[4],a[5],a[6],a[7]);
    }
}

// ---------------- head: 256 tokens/block ----------------
__global__ __launch_bounds__(256) void k_head(const float* __restrict__ x,
                                              const float* __restrict__ Wl, const float* __restrict__ bl,
                                              const float* __restrict__ fg, float* __restrict__ h){
    __shared__ __align__(16) unsigned short WlT[512 * 40];
    __shared__ __align__(16) unsigned short As[256 * 40];
    int tid = threadIdx.x;
    int gid0 = blockIdx.x * 256;
    {
        int t = gid0 + tid;   // grid = NB*NTOK/256 exactly
        const float4* xr4 = (const float4*)(x + (size_t)t * 16);
        float cur[16]; float s2 = 0.f;
        #pragma unroll
        for (int c = 0; c < 4; c++){
            float4 v4 = xr4[c];
            cur[4*c] = v4.x; cur[4*c+1] = v4.y; cur[4*c+2] = v4.z; cur[4*c+3] = v4.w;
        }
        #pragma unroll
        for (int d = 0; d < 16; d++) s2 += cur[d]*cur[d];
        float sc = fg[0] / fmaxf(sqrtf(s2) * 0.25f, 1e-5f);
        unsigned int* dd = (unsigned int*)(As + tid * 40);
        #pragma unroll
        for (int i = 0; i < 8; i++) dd[i] = packbf(cur[2*i]*sc, cur[2*i+1]*sc);
        dd[8] = 0x00003f80u;
        #pragma unroll
        for (int i = 9; i < 16; i++) dd[i] = 0u;
    }
    int w = tid >> 6, lane = tid & 63, m16 = lane & 15, quad = lane >> 4;
    f32x4 vm[4];
    #pragma unroll
    for (int i = 0; i < 4; i++) vm[i] = (f32x4){-3e38f,-3e38f,-3e38f,-3e38f};
    for (int half = 0; half < 2; half++){
        __syncthreads();
        for (int i = tid; i < 8192; i += 256){
            int d = i >> 9, c = i & 511;
            WlT[c*40 + d] = f2bf(Wl[(size_t)d*1024 + half*512 + c]);
        }
        for (int i = tid; i < 512; i += 256){
            WlT[i*40 + 16] = f2bf(bl[half*512 + i]);
            WlT[i*40 + 17] = 0;
            unsigned int* zz = (unsigned int*)(WlT + i*40 + 18);
            #pragma unroll
            for (int k = 0; k < 7; k++) zz[k] = 0u;
        }
        __syncthreads();
        s16x8 af[4];
        #pragma unroll
        for (int i = 0; i < 4; i++)
            af[i] = *(const s16x8*)(As + (w*64 + i*16 + m16)*40 + quad*8);
        f32x4 zacc = {0,0,0,0};
        for (int nt = 0; nt < 32; nt++){
            s16x8 bf = *(const s16x8*)(WlT + (nt*16 + m16)*40 + quad*8);
            #pragma unroll
            for (int i = 0; i < 4; i++){
                f32x4 r = __builtin_amdgcn_mfma_f32_16x16x32_bf16(af[i], bf, zacc, 0,0,0);
                #pragma unroll
                for (int reg = 0; reg < 4; reg++)
                    vm[i][reg] = fmaxf(vm[i][reg], r[reg]);
            }
        }
    }
    #pragma unroll
    for (int i = 0; i < 4; i++){
        #pragma unroll
        for (int off = 1; off < 16; off <<= 1){
            #pragma unroll
            for (int reg = 0; reg < 4; reg++)
                vm[i][reg] = fmaxf(vm[i][reg], __shfl_xor(vm[i][reg], off, 64));
        }
    }
    if (m16 == 0){
        #pragma unroll
        for (int i = 0; i < 4; i++){
            int t0 = gid0 + w*64 + i*16 + quad*4;
            #pragma unroll
            for (int reg = 0; reg < 4; reg++)
                h[t0 + reg] = vm[i][reg];
        }
    }
}

// ---------------- final MLP ----------------
__global__ __launch_bounds__(256) void k_final(const float* __restrict__ h,
                                               const float* __restrict__ W1, const float* __restrict__ b1,
                                               const float* __restrict__ W2, const float* __restrict__ b2,
                                               float* __restrict__ out){
    int b = blockIdx.x;
    int tid = threadIdx.x;
    int j = tid & 31, part = tid >> 5;
    float acc = 0.f;
    for (int i = part; i < NTOK; i += 8)
        acc += h[(size_t)b*NTOK + i] * W1[(size_t)i*32 + j];
    __shared__ float red[8][33];
    red[part][j] = acc;
    __syncthreads();
    if (tid < 32){
        float s = b1[tid];
        #pragma unroll
        for (int p = 0; p < 8; p++) s += red[p][tid];
        s = fmaxf(s, 0.f);
        red[0][tid] = s * W2[tid];
    }
    __syncthreads();
    if (tid == 0){
        float s = b2[0];
        #pragma unroll
        for (int jj = 0; jj < 32; jj++) s += red[0][jj];
        out[b] = s;
    }
}

extern "C" void kernel_launch(void* const* d_in, const int* in_sizes, int n_in,
                              void* d_out, int out_size, void* d_ws, size_t ws_size,
                              hipStream_t stream){
    const int*   kmer  = (const int*)d_in[0];
    const float* emb   = (const float*)d_in[1];
    const float* ps    = (const float*)d_in[2];
    const float* ng    = (const float*)d_in[3];
    const float* Wh    = (const float*)d_in[4];
    const float* bh    = (const float*)d_in[5];
    const float* Wqk   = (const float*)d_in[6];
    const float* bqk   = (const float*)d_in[7];
    const float* gamma = (const float*)d_in[8];
    const float* beta  = (const float*)d_in[9];
    const float* Wo    = (const float*)d_in[10];
    const float* bo    = (const float*)d_in[11];
    const float* fg    = (const float*)d_in[12];
    const float* Wl    = (const float*)d_in[13];
    const float* bl    = (const float*)d_in[14];
    const float* W1    = (const float*)d_in[15];
    const float* b1    = (const float*)d_in[16];
    const float* W2    = (const float*)d_in[17];
    const float* b2    = (const float*)d_in[18];
    float* out = (float*)d_out;

    char* wsp = (char*)d_ws;
    float* x = (float*)wsp;                     wsp += (size_t)NB*NTOK*16*4;
    unsigned short* qk = (unsigned short*)wsp;  wsp += (size_t)NB*NPAD*128*2;
    unsigned short* vT = (unsigned short*)wsp;  wsp += (size_t)NB*32*NPAD*2;
    unsigned short* gateb = (unsigned short*)wsp; wsp += (size_t)NB*NPAD*32*2;
    float* linkvp = (float*)wsp;                wsp += (size_t)4*NB*32*128*4;
    float* rope = (float*)wsp;                  wsp += (size_t)NPAD*32*4;
    float* h = (float*)wsp;                     wsp += (size_t)NB*NTOK*4;

    k_embed<<<(NB*NTOK + 255)/256, 256, 0, stream>>>(kmer, emb, ps, x, rope);
    for (int layer = 0; layer < NLAY; layer++){
        k_pre<<<NB*4, 512, 0, stream>>>(x, Wh, bh, Wqk, bqk, ng, gamma, beta, rope, layer, qk, vT, gateb, linkvp);
        k_quad<<<NB*NGRP, 512, 0, stream>>>(qk, vT, gateb, linkvp, rope, gamma, beta, layer, Wo, bo, x);
    }
    k_head<<<NB*NTOK/256, 256, 0, stream>>>(x, Wl, bl, fg, h);
    k_final<<<NB, 256, 0, stream>>>(h, W1, b1, W2, b2, out);
}

// Round 3
// 749.976 us; speedup vs baseline: 1.6583x; 1.6583x over previous
//
#include <hip/hip_runtime.h>

typedef short s16x8 __attribute__((ext_vector_type(8)));
typedef float f32x4 __attribute__((ext_vector_type(4)));

#define NB    128
#define NTOK  996
#define NPAD  1024
#define NGRP  4
#define GSZ   256
#define NLAY  8

__device__ __forceinline__ float bf2f(unsigned short u){
    unsigned int v = ((unsigned int)u) << 16;
    return __uint_as_float(v);
}
__device__ __forceinline__ unsigned short f2bf(float f){
    unsigned int x = __float_as_uint(f);
    unsigned int r = (x + 0x7fffu + ((x >> 16) & 1u)) >> 16;
    return (unsigned short)r;
}
__device__ __forceinline__ unsigned int packbf(float a, float b){
    return (unsigned int)f2bf(a) | ((unsigned int)f2bf(b) << 16);
}
__device__ __forceinline__ float silu(float v){
    return v / (1.0f + __expf(-v));
}

// LDS-only barrier: __syncthreads() emits s_waitcnt vmcnt(0) before s_barrier,
// draining in-flight global loads/stores. Our in-loop barriers only protect
// LDS producer->consumer, so wait lgkmcnt only. Global stores drain at kernel
// end; prefetched loads get counted vmcnt waits at their USE.
__device__ __forceinline__ void bar_lds(){
    asm volatile("s_waitcnt lgkmcnt(0)\n\ts_barrier" ::: "memory");
}

// derive one MFMA A/B fragment (8 dims at d0) of gamma*qk+beta with rotary
__device__ __forceinline__ s16x8 derive_core(const unsigned short* __restrict__ qrow, int d0,
        float4 g0, float4 g1, float4 b0, float4 b1,
        const float* __restrict__ rp, bool rot){
    uint4 u = *(const uint4*)(qrow + d0);
    float y0 = bf2f((unsigned short)(u.x & 0xffffu))*g0.x + b0.x;
    float y1 = bf2f((unsigned short)(u.x >> 16))    *g0.y + b0.y;
    float y2 = bf2f((unsigned short)(u.y & 0xffffu))*g0.z + b0.z;
    float y3 = bf2f((unsigned short)(u.y >> 16))    *g0.w + b0.w;
    float y4 = bf2f((unsigned short)(u.z & 0xffffu))*g1.x + b1.x;
    float y5 = bf2f((unsigned short)(u.z >> 16))    *g1.y + b1.y;
    float y6 = bf2f((unsigned short)(u.w & 0xffffu))*g1.z + b1.z;
    float y7 = bf2f((unsigned short)(u.w >> 16))    *g1.w + b1.w;
    if (rot){
        float4 c4 = *(const float4*)(rp);
        float4 s4 = *(const float4*)(rp + 16);
        float a;
        a = y0; y0 = a*c4.x - y1*s4.x; y1 = y1*c4.x + a*s4.x;
        a = y2; y2 = a*c4.y - y3*s4.y; y3 = y3*c4.y + a*s4.y;
        a = y4; y4 = a*c4.z - y5*s4.z; y5 = y5*c4.z + a*s4.z;
        a = y6; y6 = a*c4.w - y7*s4.w; y7 = y7*c4.w + a*s4.w;
    }
    union { unsigned int uu[4]; s16x8 s; } r;
    r.uu[0] = packbf(y0, y1);
    r.uu[1] = packbf(y2, y3);
    r.uu[2] = packbf(y4, y5);
    r.uu[3] = packbf(y6, y7);
    return r.s;
}

// ---------------- embed + positional (+ rope table) ----------------
__global__ __launch_bounds__(256) void k_embed(const int* __restrict__ kmer,
                                               const float* __restrict__ emb,
                                               const float* __restrict__ ps,
                                               float* __restrict__ x,
                                               float* __restrict__ rope){
    int gid = blockIdx.x * 256 + threadIdx.x;
    if (gid < NPAD){
        float tf2 = (float)gid;
        #pragma unroll
        for (int i = 0; i < 16; i++){
            float inv = expf(((float)(2*i) / 32.0f) * -9.210340371976184f);
            float ang = tf2 * inv;
            rope[gid*32 + i]      = cosf(ang);
            rope[gid*32 + 16 + i] = sinf(ang);
        }
    }
    if (gid >= NB * NTOK) return;
    int b = gid / NTOK;
    int tt = gid - b * NTOK;
    int idx = kmer[gid];
    const float* er = emb + (size_t)idx * 16;
    float pscale = ps[0];
    float tf = (float)tt;
    float* xr = x + (size_t)gid * 16;
    #pragma unroll
    for (int i = 0; i < 8; i++){
        float inv = expf(((float)(2*i) / 16.0f) * -9.210340371976184f);
        float ang = tf * inv;
        xr[i]     = er[i]     + sinf(ang) * pscale;
        xr[8 + i] = er[8 + i] + cosf(ang) * pscale;
    }
}

// ---------------- per-layer tokenwise + fused lin_kv partial ----------------
// R3: 512 threads, lgkmcnt-only barriers (global stores never drained in-loop
// -> inline qk/gateb stores are fine, register deferral dropped). vT/linkvp
// via wave-local LDS transpose -> coalesced 16B stores. MFMA K=32 fragments
// need 32-short rows: stride 40 (R1 bug: 24 -> quad==3 read next row -> NaN).
// LDS phase-aliased: WcT [0,15360); As [15360,35840) dead after bfr preload,
// overlaid by LkT [15360,50176); Vt [50176,58880). launch_bounds(512,2) -
// (512,4) capped VGPR at 64 and spilled ~150MB scratch (R2 regression).
__global__ __launch_bounds__(512, 2) void k_pre(const float* __restrict__ x,
                                             const float* __restrict__ Wh, const float* __restrict__ bh,
                                             const float* __restrict__ Wqk, const float* __restrict__ bqk,
                                             const float* __restrict__ norm_g,
                                             const float* __restrict__ gamma, const float* __restrict__ beta,
                                             const float* __restrict__ rope, int layer,
                                             unsigned short* __restrict__ qk,
                                             unsigned short* __restrict__ vT,
                                             unsigned short* __restrict__ gateb,
                                             float* __restrict__ linkvp){
    __shared__ __align__(16) unsigned char sm[58880];
    unsigned short* WcT = (unsigned short*)sm;             // [192][40] dims0..15,16=bias,17..31=0
    unsigned short* As  = (unsigned short*)(sm + 15360);   // [256][40] token fragments (phase 1)
    unsigned short* LkT = (unsigned short*)(sm + 15360);   // [128][136] lin_k chunk (phase 2, aliases As)
    unsigned short* Vt  = (unsigned short*)(sm + 50176);   // [32][136]  v chunk
    int tid = threadIdx.x;
    int qt = blockIdx.x & 3, b = blockIdx.x >> 2;
    const float* Whl = Wh  + (size_t)layer * 1024;
    const float* Wql = Wqk + (size_t)layer * 2048;
    const float* gLin = gamma + (size_t)layer * 512 + 384;
    const float* bLin = beta  + (size_t)layer * 512 + 384;
    for (int i = tid; i < 1024; i += 512){ int d = i >> 6, c2 = i & 63;  WcT[c2*40 + d] = f2bf(Whl[i]); }
    for (int i = tid; i < 2048; i += 512){ int d = i >> 7, c2 = i & 127; WcT[(64 + c2)*40 + d] = f2bf(Wql[i]); }
    if (tid < 192){
        int i = tid;
        float bv = (i < 64) ? bh[layer*64 + i] : bqk[layer*128 + (i - 64)];
        WcT[i*40 + 16] = f2bf(bv);
        WcT[i*40 + 17] = 0;
        unsigned int* zz = (unsigned int*)(WcT + i*40 + 18);
        #pragma unroll
        for (int k = 0; k < 7; k++) zz[k] = 0u;
    }
    float g = norm_g[layer];
    if (tid < 256){
        int tt = qt*256 + tid;
        int tsafe = tt < NTOK ? tt : (NTOK - 1);
        unsigned int* dd = (unsigned int*)(As + tid * 40);
        const float4* xr4 = (const float4*)(x + ((size_t)b*NTOK + tsafe) * 16);
        float cur[16];
        float s2 = 0.f;
        #pragma unroll
        for (int c2 = 0; c2 < 4; c2++){
            float4 v4 = xr4[c2];
            cur[4*c2] = v4.x; cur[4*c2+1] = v4.y; cur[4*c2+2] = v4.z; cur[4*c2+3] = v4.w;
        }
        #pragma unroll
        for (int d = 0; d < 16; d++) s2 += cur[d]*cur[d];
        float sc = g / fmaxf(sqrtf(s2) * 0.25f, 1e-5f);
        #pragma unroll
        for (int i = 0; i < 4; i++) dd[4 + i] = packbf(cur[8 + 2*i]*sc, cur[9 + 2*i]*sc);
        dd[8] = 0x00003f80u; // dim16 = 1.0 (bias lane)
        #pragma unroll
        for (int i = 9; i < 16; i++) dd[i] = 0u;
        if (tid < 255){      // write NEXT token's shifted half (structural shift)
            unsigned int* ddn = (unsigned int*)(As + (tid+1) * 40);
            #pragma unroll
            for (int i = 0; i < 4; i++) ddn[i] = packbf(cur[2*i]*sc, cur[2*i+1]*sc);
        }
        if (tid == 0){
            if (tt == 0){
                dd[0] = 0u; dd[1] = 0u; dd[2] = 0u; dd[3] = 0u;
            } else {
                const float4* xp4 = (const float4*)(x + ((size_t)b*NTOK + tt - 1) * 16);
                float prv[16]; float p2 = 0.f;
                #pragma unroll
                for (int c2 = 0; c2 < 4; c2++){
                    float4 v4 = xp4[c2];
                    prv[4*c2] = v4.x; prv[4*c2+1] = v4.y; prv[4*c2+2] = v4.z; prv[4*c2+3] = v4.w;
                }
                #pragma unroll
                for (int d = 0; d < 16; d++) p2 += prv[d]*prv[d];
                float sp = g / fmaxf(sqrtf(p2) * 0.25f, 1e-5f);
                #pragma unroll
                for (int i = 0; i < 4; i++) dd[i] = packbf(prv[2*i]*sp, prv[2*i+1]*sp);
            }
        }
    }
    bar_lds();   // WcT + As ready
    int w = tid >> 6, lane = tid & 63, m16 = lane & 15, quad = lane >> 4;
    s16x8 bfr[2];
    #pragma unroll
    for (int nt = 0; nt < 2; nt++)
        bfr[nt] = *(const s16x8*)(As + (w*32 + nt*16 + m16)*40 + quad*8);
    bar_lds();   // As dead; LkT/Vt region reusable
    f32x4 zacc = {0.f,0.f,0.f,0.f};
    f32x4 lacc[2] = {{0,0,0,0},{0,0,0,0}};
    unsigned int vpk[2][2][2];   // v (masked) for the coalesced epilogue transpose
    int c = w*16 + m16;          // column in 128-token chunk staging
    #pragma unroll
    for (int nt = 0; nt < 2; nt++){
        int ttk = qt*256 + w*32 + nt*16 + m16;
        bool tv = ttk < NTOK;
        size_t rowq = (size_t)b*NPAD + ttk;
        #pragma unroll
        for (int mi = 0; mi < 12; mi++){
            s16x8 wfm = *(const s16x8*)(WcT + (mi*16 + m16)*40 + quad*8);
            f32x4 r = __builtin_amdgcn_mfma_f32_16x16x32_bf16(wfm, bfr[nt], zacc, 0, 0, 0);
            float sv[4];
            #pragma unroll
            for (int reg = 0; reg < 4; reg++) sv[reg] = silu(r[reg]);
            int wc0 = mi*16 + quad*4;
            if (mi < 2){
                unsigned short p0 = tv ? f2bf(sv[0]) : (unsigned short)0;
                unsigned short p1 = tv ? f2bf(sv[1]) : (unsigned short)0;
                unsigned short p2 = tv ? f2bf(sv[2]) : (unsigned short)0;
                unsigned short p3 = tv ? f2bf(sv[3]) : (unsigned short)0;
                Vt[(wc0+0)*136 + c] = p0;
                Vt[(wc0+1)*136 + c] = p1;
                Vt[(wc0+2)*136 + c] = p2;
                Vt[(wc0+3)*136 + c] = p3;
                vpk[nt][mi][0] = (unsigned int)p0 | ((unsigned int)p1 << 16);
                vpk[nt][mi][1] = (unsigned int)p2 | ((unsigned int)p3 << 16);
            } else if (mi < 4){
                *(uint2*)(gateb + rowq*32 + (wc0 - 32)) = make_uint2(packbf(sv[0],sv[1]), packbf(sv[2],sv[3]));
            } else {
                int qd = wc0 - 64;
                *(uint2*)(qk + rowq*128 + qd) = make_uint2(packbf(sv[0],sv[1]), packbf(sv[2],sv[3]));
                float y0 = sv[0]*gLin[qd]   + bLin[qd];
                float y1 = sv[1]*gLin[qd+1] + bLin[qd+1];
                float y2 = sv[2]*gLin[qd+2] + bLin[qd+2];
                float y3 = sv[3]*gLin[qd+3] + bLin[qd+3];
                if (qd < 32){
                    const float* rp = rope + ttk*32 + (qd >> 1);
                    float c0 = rp[0], s0 = rp[16], c1 = rp[1], s1 = rp[17];
                    float a;
                    a = y0; y0 = a*c0 - y1*s0; y1 = y1*c0 + a*s0;
                    a = y2; y2 = a*c1 - y3*s1; y3 = y3*c1 + a*s1;
                }
                LkT[(qd+0)*136 + c] = f2bf(y0);
                LkT[(qd+1)*136 + c] = f2bf(y1);
                LkT[(qd+2)*136 + c] = f2bf(y2);
                LkT[(qd+3)*136 + c] = f2bf(y3);
            }
        }
        bar_lds();   // LkT/Vt 128-token chunk ready (global stores NOT drained)
        #pragma unroll
        for (int ks2 = 0; ks2 < 4; ks2++){
            s16x8 a  = *(const s16x8*)(LkT + (w*16 + m16)*136 + ks2*32 + quad*8);
            s16x8 b0 = *(const s16x8*)(Vt + (m16)*136 + ks2*32 + quad*8);
            s16x8 b1 = *(const s16x8*)(Vt + (16 + m16)*136 + ks2*32 + quad*8);
            lacc[0] = __builtin_amdgcn_mfma_f32_16x16x32_bf16(a, b0, lacc[0], 0,0,0);
            lacc[1] = __builtin_amdgcn_mfma_f32_16x16x32_bf16(a, b1, lacc[1], 0,0,0);
        }
        bar_lds();   // chunk reads done (also frees whole LDS for epilogue)
    }
    // vT: wave-local LDS transpose -> coalesced 16B stores (aliases dead WcT/As)
    {
        unsigned short* mv = (unsigned short*)sm + w*1280;   // [32 e][40 tok-pad]
        #pragma unroll
        for (int nt = 0; nt < 2; nt++){
            #pragma unroll
            for (int mi = 0; mi < 2; mi++){
                int e0 = mi*16 + quad*4;
                mv[(e0+0)*40 + nt*16 + m16] = (unsigned short)(vpk[nt][mi][0] & 0xffffu);
                mv[(e0+1)*40 + nt*16 + m16] = (unsigned short)(vpk[nt][mi][0] >> 16);
                mv[(e0+2)*40 + nt*16 + m16] = (unsigned short)(vpk[nt][mi][1] & 0xffffu);
                mv[(e0+3)*40 + nt*16 + m16] = (unsigned short)(vpk[nt][mi][1] >> 16);
            }
        }
        #pragma unroll
        for (int r2 = 0; r2 < 2; r2++){
            int e = r2*16 + (lane >> 2);
            int cc = (lane & 3) * 8;
            s16x8 vv = *(const s16x8*)(mv + e*40 + cc);
            *(s16x8*)(vT + ((size_t)b*32 + e)*NPAD + qt*256 + w*32 + cc) = vv;
        }
    }
    // linkv partial: wave-local LDS transpose -> coalesced float4 stores
    {
        float* ml = (float*)(sm + 20480) + w*512;   // [32 e][16 d]
        const float invn = 1.0f / 996.0f;
        #pragma unroll
        for (int j = 0; j < 2; j++)
            #pragma unroll
            for (int reg = 0; reg < 4; reg++)
                ml[(j*16 + m16)*16 + quad*4 + reg] = lacc[j][reg] * invn;
        #pragma unroll
        for (int r2 = 0; r2 < 2; r2++){
            int e = r2*16 + (lane >> 2);
            int dc = (lane & 3) * 4;
            float4 vv = *(const float4*)(ml + e*16 + dc);
            *(float4*)(linkvp + (((size_t)qt*NB + b)*32 + e)*128 + w*16 + dc) = vv;
        }
    }
}

// ---------------- quad attention + lin_out + gate + Wo + residual ----------------
// R15 structure + R3 pipeline: lgkmcnt-only barriers mean the one-chunk-ahead
// qk/rope register prefetch and the V-fragment hoist genuinely stay in flight
// across barriers (the compiler then emits COUNTED vmcnt waits at the use).
// launch_bounds(512,2) (cap 256; caps<=128 provably spill ~150MB scratch RMW).
// LDS row strides stay multiples of 8 shorts (R17 lesson).
#define KD_BYTES (64*136*2)
#define PW_BYTES (8*32*72*2)
__global__ __launch_bounds__(512, 2) void k_quad(const unsigned short* __restrict__ qk,
                                              const unsigned short* __restrict__ vT,
                                              const unsigned short* __restrict__ gateb,
                                              const float* __restrict__ linkvp,
                                              const float* __restrict__ rope,
                                              const float* __restrict__ gamma, const float* __restrict__ beta,
                                              int layer,
                                              const float* __restrict__ Wo, const float* __restrict__ bo,
                                              float* __restrict__ x){
    __shared__ __align__(16) unsigned char smem[KD_BYTES + PW_BYTES];
    __shared__ __align__(16) unsigned short LkBs[32 * 136]; // lin_kv B-fragments [e][d]
    __shared__ float sWo[512];
    __shared__ float sbo[16];
    unsigned short* Kd = (unsigned short*)smem;
    unsigned short* Pw = (unsigned short*)(smem + KD_BYTES);
    int tid = threadIdx.x;
    int blk = blockIdx.x;
    int g = blk & 3, b = blk >> 2;
    int tg0 = g * GSZ;
    const float* gamL = gamma + (size_t)layer * 512;
    const float* betL = beta  + (size_t)layer * 512;
    sWo[tid] = Wo[layer*512 + tid];
    if (tid < 16) sbo[tid] = bo[layer*16 + tid];

    int w = tid >> 6, lane = tid & 63, m16 = lane & 15, quad = lane >> 4;

    // ---- derive quad_q fragments into registers (wave w owns q rows [w*32, w*32+32)) ----
    int tqA = tg0 + w*32 + m16;
    int tqB = tqA + 16;
    const unsigned short* qrowA = qk + ((size_t)b*NPAD + tqA)*128;
    const unsigned short* qrowB = qk + ((size_t)b*NPAD + tqB)*128;
    const float* rpA = rope + tqA*32 + quad*4;
    const float* rpB = rope + tqB*32 + quad*4;
    s16x8 qf[2][4];
    #pragma unroll
    for (int ks = 0; ks < 4; ks++){
        int d0 = ks*32 + quad*8;
        float4 g0 = *(const float4*)(gamL + d0), g1 = *(const float4*)(gamL + d0 + 4);
        float4 b0 = *(const float4*)(betL + d0), b1 = *(const float4*)(betL + d0 + 4);
        bool rot = (ks == 0) && (quad < 4);
        qf[0][ks] = derive_core(qrowA, d0, g0,g1,b0,b1, rpA, rot);
        qf[1][ks] = derive_core(qrowB, d0, g0,g1,b0,b1, rpB, rot);
    }

    const float* gK = gamL + 256;
    const float* bK = betL + 256;
    f32x4 oacc[2][2] = {{{0,0,0,0},{0,0,0,0}},{{0,0,0,0},{0,0,0,0}}};
    unsigned short* myP = Pw + w*32*72;   // 32 rows per wave (both sub-tiles)

    // ---- K-staging geometry + one-chunk-ahead register prefetch ----
    int kr = tid >> 3, seg = (tid & 7) * 16;
    uint4 pku0, pku1;
    float4 prc0, prc1, prs0, prs1;
    auto LOADK = [&](int ch){
        int tk = tg0 + ch*64 + kr;
        const unsigned short* krow = qk + ((size_t)b*NPAD + tk)*128 + seg;
        pku0 = ((const uint4*)krow)[0];
        pku1 = ((const uint4*)krow)[1];
        const float* rpk = rope + (seg < 32 ? (tk*32 + (seg >> 1)) : 0);
        prc0 = *(const float4*)(rpk);
        prs0 = *(const float4*)(rpk + 16);
        prc1 = *(const float4*)(rpk + 4);
        prs1 = *(const float4*)(rpk + 20);
    };
    LOADK(0);

    for (int ch = 0; ch < 4; ch++){
        // V-fragment prefetch: consumed by PV at chunk end; latency hidden
        s16x8 vf[2][2];
        #pragma unroll
        for (int ks2 = 0; ks2 < 2; ks2++){
            vf[ks2][0] = *(const s16x8*)(vT + ((size_t)b*32 + m16)*NPAD + tg0 + ch*64 + ks2*32 + quad*8);
            vf[ks2][1] = *(const s16x8*)(vT + ((size_t)b*32 + 16 + m16)*NPAD + tg0 + ch*64 + ks2*32 + quad*8);
        }
        // derive this chunk's K from prefetched regs (no LDS/global dependency)
        uint4 kd0, kd1;
        {
            #pragma unroll
            for (int h = 0; h < 2; h++){
                uint4 u = h ? pku1 : pku0;
                unsigned int uu[4] = {u.x, u.y, u.z, u.w};
                float y[8];
                #pragma unroll
                for (int k = 0; k < 4; k++){
                    int d = h*8 + 2*k;
                    y[2*k]   = bf2f((unsigned short)(uu[k] & 0xffffu)) * gK[seg + d]     + bK[seg + d];
                    y[2*k+1] = bf2f((unsigned short)(uu[k] >> 16))     * gK[seg + d + 1] + bK[seg + d + 1];
                }
                if (seg < 32){
                    float cc[4], ss[4];
                    if (h){ cc[0]=prc1.x; cc[1]=prc1.y; cc[2]=prc1.z; cc[3]=prc1.w;
                            ss[0]=prs1.x; ss[1]=prs1.y; ss[2]=prs1.z; ss[3]=prs1.w; }
                    else  { cc[0]=prc0.x; cc[1]=prc0.y; cc[2]=prc0.z; cc[3]=prc0.w;
                            ss[0]=prs0.x; ss[1]=prs0.y; ss[2]=prs0.z; ss[3]=prs0.w; }
                    #pragma unroll
                    for (int p2 = 0; p2 < 4; p2++){
                        float a = y[2*p2], d2 = y[2*p2+1];
                        y[2*p2]   = a*cc[p2] - d2*ss[p2];
                        y[2*p2+1] = d2*cc[p2] + a*ss[p2];
                    }
                }
                uint4 kk = make_uint4(packbf(y[0],y[1]), packbf(y[2],y[3]),
                                      packbf(y[4],y[5]), packbf(y[6],y[7]));
                if (h) kd1 = kk; else kd0 = kk;
            }
        }
        bar_lds();   // all waves done reading prev Kd; covers sWo on ch==0
        *(uint4*)(Kd + kr*136 + seg)     = kd0;
        *(uint4*)(Kd + kr*136 + seg + 8) = kd1;
        if (ch < 3) LOADK(ch + 1);   // next chunk's qk/rope loads stay in flight across barrier
        bar_lds();   // Kd ready (lgkmcnt only; LOADK/vf remain outstanding)
        // ---- S for BOTH q sub-tiles per np (kf read once, feeds 4 MFMAs) ----
        #pragma unroll
        for (int np = 0; np < 2; np++){
            f32x4 s00 = {0,0,0,0}, s01 = {0,0,0,0}, s10 = {0,0,0,0}, s11 = {0,0,0,0};
            #pragma unroll
            for (int ks = 0; ks < 4; ks++){
                s16x8 kf0 = *(const s16x8*)(Kd + ((np*2  )*16 + m16)*136 + ks*32 + quad*8);
                s16x8 kf1 = *(const s16x8*)(Kd + ((np*2+1)*16 + m16)*136 + ks*32 + quad*8);
                s00 = __builtin_amdgcn_mfma_f32_16x16x32_bf16(qf[0][ks], kf0, s00, 0,0,0);
                s01 = __builtin_amdgcn_mfma_f32_16x16x32_bf16(qf[0][ks], kf1, s01, 0,0,0);
                s10 = __builtin_amdgcn_mfma_f32_16x16x32_bf16(qf[1][ks], kf0, s10, 0,0,0);
                s11 = __builtin_amdgcn_mfma_f32_16x16x32_bf16(qf[1][ks], kf1, s11, 0,0,0);
            }
            #pragma unroll
            for (int j = 0; j < 2; j++){
                int kl = (np*2 + j)*16 + m16;
                bool kv = (tg0 + ch*64 + kl) < NTOK;
                #pragma unroll
                for (int reg = 0; reg < 4; reg++){
                    float a0 = fmaxf(j ? s01[reg] : s00[reg], 0.0f);
                    float a1 = fmaxf(j ? s11[reg] : s10[reg], 0.0f);
                    a0 = a0 * a0;
                    a1 = a1 * a1;
                    myP[(quad*4 + reg)*72 + kl]      = kv ? f2bf(a0) : (unsigned short)0;
                    myP[(16 + quad*4 + reg)*72 + kl] = kv ? f2bf(a1) : (unsigned short)0;
                }
            }
        }
        // ---- PV: both sub-tiles, V fragments from registers ----
        #pragma unroll
        for (int i = 0; i < 2; i++){
            #pragma unroll
            for (int ks2 = 0; ks2 < 2; ks2++){
                s16x8 pa = *(const s16x8*)(myP + (i*16 + m16)*72 + ks2*32 + quad*8);
                oacc[i][0] = __builtin_amdgcn_mfma_f32_16x16x32_bf16(pa, vf[ks2][0], oacc[i][0], 0,0,0);
                oacc[i][1] = __builtin_amdgcn_mfma_f32_16x16x32_bf16(pa, vf[ks2][1], oacc[i][1], 0,0,0);
            }
        }
    }
    // fold the (1/256)^2 quad scale
    const float qsc = 1.0f / 65536.0f;
    #pragma unroll
    for (int i = 0; i < 2; i++)
        #pragma unroll
        for (int j = 0; j < 2; j++)
            oacc[i][j] = oacc[i][j] * qsc;
    // ---- stage lin_kv B-fragments: sum 4 fp32 partials -> bf16 LDS ----
    {
        int e = tid >> 4, dbase = (tid & 15) * 8;
        float s[8];
        #pragma unroll
        for (int k = 0; k < 8; k++) s[k] = 0.f;
        #pragma unroll
        for (int part = 0; part < 4; part++){
            const float* src = linkvp + (((size_t)part*NB + b)*32 + e)*128 + dbase;
            float4 u0 = *(const float4*)src;
            float4 u1 = *(const float4*)(src + 4);
            s[0]+=u0.x; s[1]+=u0.y; s[2]+=u0.z; s[3]+=u0.w;
            s[4]+=u1.x; s[5]+=u1.y; s[6]+=u1.z; s[7]+=u1.w;
        }
        unsigned int* dst = (unsigned int*)(LkBs + e*136 + dbase);
        #pragma unroll
        for (int k = 0; k < 4; k++) dst[k] = packbf(s[2*k], s[2*k+1]);
    }
    bar_lds();   // LkBs ready; all waves done with Kd/Pw (safe for O-stage reuse)
    // ---- epilogue operand prefetch (hidden under lin path) ----
    int pr = lane >> 1, dp2 = (lane & 1) * 8;
    int p = tg0 + w*32 + pr;
    bool pvld = p < NTOK;
    int psafe = pvld ? p : (NTOK - 1);
    const unsigned short* gr = gateb + ((size_t)b*NPAD + psafe)*32;
    uint4 egu[4];
    #pragma unroll
    for (int eh = 0; eh < 4; eh++) egu[eh] = *(const uint4*)(gr + eh*8);
    float* xr = x + ((size_t)b*NTOK + psafe)*16 + dp2;
    float4 ex0 = *(const float4*)xr;
    float4 ex1 = *(const float4*)(xr + 4);
    // ---- lin path: lin_q (in-register derive) @ LkBs ----
    {
        const float* gamQ = gamL + 128;
        const float* betQ = betL + 128;
        #pragma unroll
        for (int ks = 0; ks < 4; ks++){
            int d0 = ks*32 + quad*8;
            float4 g0 = *(const float4*)(gamQ + d0), g1 = *(const float4*)(gamQ + d0 + 4);
            float4 b0 = *(const float4*)(betQ + d0), b1 = *(const float4*)(betQ + d0 + 4);
            bool rot = (ks == 0) && (quad < 4);
            s16x8 lf0 = derive_core(qrowA, d0, g0,g1,b0,b1, rpA, rot);
            s16x8 lf1 = derive_core(qrowB, d0, g0,g1,b0,b1, rpB, rot);
            #pragma unroll
            for (int j = 0; j < 2; j++){
                s16x8 lb = *(const s16x8*)(LkBs + (j*16 + m16)*136 + ks*32 + quad*8);
                oacc[0][j] = __builtin_amdgcn_mfma_f32_16x16x32_bf16(lf0, lb, oacc[0][j], 0,0,0);
                oacc[1][j] = __builtin_amdgcn_mfma_f32_16x16x32_bf16(lf1, lb, oacc[1][j], 0,0,0);
            }
        }
    }
    // ---- stage O (per-wave slice of the smem arena, as floats; within-wave only) ----
    float* Obw = (float*)smem + w*1056;  // 32 rows x stride 33 = 4224 B/wave
    #pragma unroll
    for (int i = 0; i < 2; i++)
        #pragma unroll
        for (int j = 0; j < 2; j++)
            #pragma unroll
            for (int reg = 0; reg < 4; reg++)
                Obw[(i*16 + quad*4 + reg)*33 + j*16 + m16] = oacc[i][j][reg];
    // ---- epilogue: x += (gate .* O) @ Wo + bo (per-wave rows, operands preloaded) ----
    if (pvld){
        float a[8] = { sbo[dp2]+ex0.x, sbo[dp2+1]+ex0.y, sbo[dp2+2]+ex0.z, sbo[dp2+3]+ex0.w,
                       sbo[dp2+4]+ex1.x, sbo[dp2+5]+ex1.y, sbo[dp2+6]+ex1.z, sbo[dp2+7]+ex1.w };
        #pragma unroll
        for (int eh = 0; eh < 4; eh++){
            unsigned int gg[4] = {egu[eh].x, egu[eh].y, egu[eh].z, egu[eh].w};
            #pragma unroll
            for (int k = 0; k < 4; k++){
                float gv0 = bf2f((unsigned short)(gg[k] & 0xffffu));
                float gv1 = bf2f((unsigned short)(gg[k] >> 16));
                int e = eh*8 + 2*k;
                float ov0 = Obw[pr*33 + e] * gv0;
                float ov1 = Obw[pr*33 + e + 1] * gv1;
                const float* wr0 = &sWo[e*16 + dp2];
                const float* wr1 = &sWo[(e+1)*16 + dp2];
                #pragma unroll
                for (int kk = 0; kk < 8; kk++) a[kk] += ov0 * wr0[kk] + ov1 * wr1[kk];
            }
        }
        *(float4*)xr = make_float4(a[0],a[1],a[2],a[3]);
        *(float4*)(xr+4) = make_float4(a[4],a[5],a[6],a[7]);
    }
}

// ---------------- head: 256 tokens/block ----------------
__global__ __launch_bounds__(256) void k_head(const float* __restrict__ x,
                                              const float* __restrict__ Wl, const float* __restrict__ bl,
                                              const float* __restrict__ fg, float* __restrict__ h){
    __shared__ __align__(16) unsigned short WlT[512 * 40];
    __shared__ __align__(16) unsigned short As[256 * 40];
    int tid = threadIdx.x;
    int gid0 = blockIdx.x * 256;
    {
        int t = gid0 + tid;   // grid = NB*NTOK/256 exactly
        const float4* xr4 = (const float4*)(x + (size_t)t * 16);
        float cur[16]; float s2 = 0.f;
        #pragma unroll
        for (int c = 0; c < 4; c++){
            float4 v4 = xr4[c];
            cur[4*c] = v4.x; cur[4*c+1] = v4.y; cur[4*c+2] = v4.z; cur[4*c+3] = v4.w;
        }
        #pragma unroll
        for (int d = 0; d < 16; d++) s2 += cur[d]*cur[d];
        float sc = fg[0] / fmaxf(sqrtf(s2) * 0.25f, 1e-5f);
        unsigned int* dd = (unsigned int*)(As + tid * 40);
        #pragma unroll
        for (int i = 0; i < 8; i++) dd[i] = packbf(cur[2*i]*sc, cur[2*i+1]*sc);
        dd[8] = 0x00003f80u;
        #pragma unroll
        for (int i = 9; i < 16; i++) dd[i] = 0u;
    }
    int w = tid >> 6, lane = tid & 63, m16 = lane & 15, quad = lane >> 4;
    f32x4 vm[4];
    #pragma unroll
    for (int i = 0; i < 4; i++) vm[i] = (f32x4){-3e38f,-3e38f,-3e38f,-3e38f};
    for (int half = 0; half < 2; half++){
        __syncthreads();
        for (int i = tid; i < 8192; i += 256){
            int d = i >> 9, c = i & 511;
            WlT[c*40 + d] = f2bf(Wl[(size_t)d*1024 + half*512 + c]);
        }
        for (int i = tid; i < 512; i += 256){
            WlT[i*40 + 16] = f2bf(bl[half*512 + i]);
            WlT[i*40 + 17] = 0;
            unsigned int* zz = (unsigned int*)(WlT + i*40 + 18);
            #pragma unroll
            for (int k = 0; k < 7; k++) zz[k] = 0u;
        }
        __syncthreads();
        s16x8 af[4];
        #pragma unroll
        for (int i = 0; i < 4; i++)
            af[i] = *(const s16x8*)(As + (w*64 + i*16 + m16)*40 + quad*8);
        f32x4 zacc = {0,0,0,0};
        for (int nt = 0; nt < 32; nt++){
            s16x8 bf = *(const s16x8*)(WlT + (nt*16 + m16)*40 + quad*8);
            #pragma unroll
            for (int i = 0; i < 4; i++){
                f32x4 r = __builtin_amdgcn_mfma_f32_16x16x32_bf16(af[i], bf, zacc, 0,0,0);
                #pragma unroll
                for (int reg = 0; reg < 4; reg++)
                    vm[i][reg] = fmaxf(vm[i][reg], r[reg]);
            }
        }
    }
    #pragma unroll
    for (int i = 0; i < 4; i++){
        #pragma unroll
        for (int off = 1; off < 16; off <<= 1){
            #pragma unroll
            for (int reg = 0; reg < 4; reg++)
                vm[i][reg] = fmaxf(vm[i][reg], __shfl_xor(vm[i][reg], off, 64));
        }
    }
    if (m16 == 0){
        #pragma unroll
        for (int i = 0; i < 4; i++){
            int t0 = gid0 + w*64 + i*16 + quad*4;
            #pragma unroll
            for (int reg = 0; reg < 4; reg++)
                h[t0 + reg] = vm[i][reg];
        }
    }
}

// ---------------- final MLP ----------------
__global__ __launch_bounds__(256) void k_final(const float* __restrict__ h,
                                               const float* __restrict__ W1, const float* __restrict__ b1,
                                               const float* __restrict__ W2, const float* __restrict__ b2,
                                               float* __restrict__ out){
    int b = blockIdx.x;
    int tid = threadIdx.x;
    int j = tid & 31, part = tid >> 5;
    float acc = 0.f;
    for (int i = part; i < NTOK; i += 8)
        acc += h[(size_t)b*NTOK + i] * W1[(size_t)i*32 + j];
    __shared__ float red[8][33];
    red[part][j] = acc;
    __syncthreads();
    if (tid < 32){
        float s = b1[tid];
        #pragma unroll
        for (int p = 0; p < 8; p++) s += red[p][tid];
        s = fmaxf(s, 0.f);
        red[0][tid] = s * W2[tid];
    }
    __syncthreads();
    if (tid == 0){
        float s = b2[0];
        #pragma unroll
        for (int jj = 0; jj < 32; jj++) s += red[0][jj];
        out[b] = s;
    }
}

extern "C" void kernel_launch(void* const* d_in, const int* in_sizes, int n_in,
                              void* d_out, int out_size, void* d_ws, size_t ws_size,
                              hipStream_t stream){
    const int*   kmer  = (const int*)d_in[0];
    const float* emb   = (const float*)d_in[1];
    const float* ps    = (const float*)d_in[2];
    const float* ng    = (const float*)d_in[3];
    const float* Wh    = (const float*)d_in[4];
    const float* bh    = (const float*)d_in[5];
    const float* Wqk   = (const float*)d_in[6];
    const float* bqk   = (const float*)d_in[7];
    const float* gamma = (const float*)d_in[8];
    const float* beta  = (const float*)d_in[9];
    const float* Wo    = (const float*)d_in[10];
    const float* bo    = (const float*)d_in[11];
    const float* fg    = (const float*)d_in[12];
    const float* Wl    = (const float*)d_in[13];
    const float* bl    = (const float*)d_in[14];
    const float* W1    = (const float*)d_in[15];
    const float* b1    = (const float*)d_in[16];
    const float* W2    = (const float*)d_in[17];
    const float* b2    = (const float*)d_in[18];
    float* out = (float*)d_out;

    char* wsp = (char*)d_ws;
    float* x = (float*)wsp;                     wsp += (size_t)NB*NTOK*16*4;
    unsigned short* qk = (unsigned short*)wsp;  wsp += (size_t)NB*NPAD*128*2;
    unsigned short* vT = (unsigned short*)wsp;  wsp += (size_t)NB*32*NPAD*2;
    unsigned short* gateb = (unsigned short*)wsp; wsp += (size_t)NB*NPAD*32*2;
    float* linkvp = (float*)wsp;                wsp += (size_t)4*NB*32*128*4;
    float* rope = (float*)wsp;                  wsp += (size_t)NPAD*32*4;
    float* h = (float*)wsp;                     wsp += (size_t)NB*NTOK*4;

    k_embed<<<(NB*NTOK + 255)/256, 256, 0, stream>>>(kmer, emb, ps, x, rope);
    for (int layer = 0; layer < NLAY; layer++){
        k_pre<<<NB*4, 512, 0, stream>>>(x, Wh, bh, Wqk, bqk, ng, gamma, beta, rope, layer, qk, vT, gateb, linkvp);
        k_quad<<<NB*NGRP, 512, 0, stream>>>(qk, vT, gateb, linkvp, rope, gamma, beta, layer, Wo, bo, x);
    }
    k_head<<<NB*NTOK/256, 256, 0, stream>>>(x, Wl, bl, fg, h);
    k_final<<<NB, 256, 0, stream>>>(h, W1, b1, W2, b2, out);
}